// Round 15
// baseline (7406.654 us; speedup 1.0000x reference)
//
#include <hip/hip_runtime.h>
#include <hip/hip_cooperative_groups.h>

namespace cg = cooperative_groups;

#define BB 256
#define SS 512
#define EE 512
#define HH 512
#define G4 2048
#define NTF 799

typedef __attribute__((ext_vector_type(8))) short bf16x8;
typedef __attribute__((ext_vector_type(4))) float f32x4;

#define MF(a, b, c) __builtin_amdgcn_mfma_f32_16x16x32_bf16((a), (b), (c), 0, 0, 0)

__device__ __forceinline__ float my_sig(float v) { return 1.0f / (1.0f + __expf(-v)); }
__device__ __forceinline__ float my_tanh(float v) { float e = __expf(2.0f * v); return 1.0f - 2.0f / (e + 1.0f); }

__device__ __forceinline__ unsigned short f2bf(float f) {   // RNE fp32->bf16
    unsigned u = __builtin_bit_cast(unsigned, f);
    u = (u + 0x7FFFu + ((u >> 16) & 1u)) >> 16;
    return (unsigned short)u;
}
__device__ __forceinline__ float bf2f(unsigned short h) {
    unsigned u = ((unsigned)h) << 16;
    return __builtin_bit_cast(float, u);
}
__device__ __forceinline__ unsigned packsplit(float f) {
    unsigned short hi = f2bf(f);
    unsigned short lo = f2bf(f - bf2f(hi));
    return ((unsigned)hi << 16) | (unsigned)lo;
}
__device__ __forceinline__ bf16x8 unhi(uint4 a, uint4 b) {
    union { unsigned u[4]; bf16x8 v; } r;
    r.u[0] = __builtin_amdgcn_perm(a.y, a.x, 0x07060302u);
    r.u[1] = __builtin_amdgcn_perm(a.w, a.z, 0x07060302u);
    r.u[2] = __builtin_amdgcn_perm(b.y, b.x, 0x07060302u);
    r.u[3] = __builtin_amdgcn_perm(b.w, b.z, 0x07060302u);
    return r.v;
}
__device__ __forceinline__ bf16x8 unlo(uint4 a, uint4 b) {
    union { unsigned u[4]; bf16x8 v; } r;
    r.u[0] = __builtin_amdgcn_perm(a.y, a.x, 0x05040100u);
    r.u[1] = __builtin_amdgcn_perm(a.w, a.z, 0x05040100u);
    r.u[2] = __builtin_amdgcn_perm(b.y, b.x, 0x05040100u);
    r.u[3] = __builtin_amdgcn_perm(b.w, b.z, 0x05040100u);
    return r.v;
}

// sc1 coherent / nt streaming accesses (asm form; verified r4-r12)
__device__ __forceinline__ void ld4_sc1(uint4& d, const unsigned* p) {
    asm volatile("global_load_dwordx4 %0, %1, off sc0 sc1" : "=v"(d) : "v"(p));
}
__device__ __forceinline__ void ld4_nt(uint4& d, const unsigned* p) {
    asm volatile("global_load_dwordx4 %0, %1, off nt" : "=v"(d) : "v"(p));
}
__device__ __forceinline__ void st_devu(unsigned* p, unsigned v) {
    __hip_atomic_store(p, v, __ATOMIC_RELAXED, __HIP_MEMORY_SCOPE_AGENT);
}
__device__ __forceinline__ unsigned ld_devu(const unsigned* p) {
    return __hip_atomic_load(p, __ATOMIC_RELAXED, __HIP_MEMORY_SCOPE_AGENT);
}

// counted wait + scheduling fence (rule #18); vmcnt retires in issue order.
// Depth-2 schedule invariant: chunk q+1 is always issued before waiting on
// chunk q, so retire-to-<=4 retires chunk q under ANY compiler interleave.
#define VMW(N)                                                                 \
    asm volatile("s_waitcnt vmcnt(" #N ")" ::: "memory");                      \
    __builtin_amdgcn_sched_barrier(0)

// ---------------------------------------------------------------------------
// Prep: split weights into bf16 hi/lo MFMA B-fragments (verbatim r8-r12).
// ---------------------------------------------------------------------------
__global__ void __launch_bounds__(256)
prep_split(const float* __restrict__ Wall, const float* __restrict__ Uall,
           const float* __restrict__ Wd,
           unsigned short* __restrict__ B1, unsigned short* __restrict__ B2)
{
    const int t = blockIdx.x * 256 + threadIdx.x;
    if (t < 262144) {
        const int lane = t & 63, wc = (t >> 6) & 3, kc = (t >> 8) & 31, cgi = t >> 13;
        const int kb = ((kc & 15) << 5) + ((lane >> 4) << 3);
        const int col = (wc << 9) + (cgi << 4) + (lane & 15);
        const float* src = (kc < 16) ? Wall : Uall;
        bf16x8 vh, vl;
#pragma unroll
        for (int j = 0; j < 8; ++j) {
            float f = src[(size_t)(kb + j) * G4 + col];
            unsigned short h16 = f2bf(f);
            vh[j] = (short)h16;
            vl[j] = (short)f2bf(f - bf2f(h16));
        }
        const int g = t >> 6;
        *(bf16x8*)(B1 + ((size_t)(g * 2 + 0) * 64 + lane) * 8) = vh;
        *(bf16x8*)(B1 + ((size_t)(g * 2 + 1) * 64 + lane) * 8) = vl;
    } else if (t < 262144 + 32768) {
        const int u = t - 262144;
        const int lane = u & 63, kch = (u >> 6) & 15, cgi = u >> 10;
        const int kb = (kch << 5) + ((lane >> 4) << 3);
        const int col = (cgi << 4) + (lane & 15);
        bf16x8 vh, vl;
#pragma unroll
        for (int j = 0; j < 8; ++j) {
            float f = Wd[(size_t)(kb + j) * HH + col];
            unsigned short h16 = f2bf(f);
            vh[j] = (short)h16;
            vl[j] = (short)f2bf(f - bf2f(h16));
        }
        const int g = u >> 6;
        *(bf16x8*)(B2 + ((size_t)(g * 2 + 0) * 64 + lane) * 8) = vh;
        *(bf16x8*)(B2 + ((size_t)(g * 2 + 1) * 64 + lane) * 8) = vl;
    }
}

// Prep: pack x -> hi|lo u32 (same layout) so fragments load as pure u32 copies.
__global__ void __launch_bounds__(256)
prep_pack(const float* __restrict__ x, unsigned* __restrict__ xpk)
{
    const size_t i = (size_t)blockIdx.x * 256 + threadIdx.x;   // 16.7M float4s
    float4 v = ((const float4*)x)[i];
    uint4 p;
    p.x = packsplit(v.x); p.y = packsplit(v.y);
    p.z = packsplit(v.z); p.w = packsplit(v.w);
    ((uint4*)xpk)[i] = p;
}

#define B1FRAG(kcv, wcv, term) (*(const bf16x8*)(B1 +                          \
    ((size_t)(((cgi * 32 + (kcv)) * 4 + (wcv)) * 2 + (term)) * 64 + lane) * 8))
#define B2FRAG(kchv, term) (*(const bf16x8*)(B2 +                              \
    ((size_t)((cgi * 16 + (kchv)) * 2 + (term)) * 64 + lane) * 8))

// gate-partial LDS index, bank-hashed (2-way max = free)
#define GPIDX(row, slot, col)                                                  \
    ((row) * 256 + (slot) * 64 + ((col) ^ (((((row) & 3) ^ (((row) >> 2) & 3))) << 4)))

// ---------------------------------------------------------------------------
// Persistent time-LSTM. 256 blocks x 512 threads. Wave (kq, ch): K-window
// kq*128, gate-col half ch*32. W/Wd frags register-resident; U streamed from
// XCD-local L2. Direct per-lane fragment loads (no LDS staging), DEPTH-2
// pipelined (xq/hq/cq[2] buffers, 32 VGPR each, ~170 peak -> no spills; r14's
// failure attributed to spilled asm-load destinations at ~280 VGPR demand).
// LDS holds only reduction partials. Sync = per-rg counter (32 blocks).
// ---------------------------------------------------------------------------
__global__ void __launch_bounds__(512) __attribute__((amdgpu_waves_per_eu(2)))
lstm_persistent(const float* __restrict__ x, const unsigned* __restrict__ xp,
                const int use_xp, const float* __restrict__ ts,
                const float* __restrict__ ball, const float* __restrict__ bu,
                const float* __restrict__ bd,
                const unsigned short* __restrict__ B1,
                const unsigned short* __restrict__ B2,
                unsigned* __restrict__ h2a, unsigned* __restrict__ h2b,
                unsigned* __restrict__ c2a, unsigned* __restrict__ c2b,
                float* __restrict__ hsum, float* __restrict__ tsT,
                unsigned* __restrict__ barv)
{
    cg::grid_group grid = cg::this_grid();
    const int tid = threadIdx.x;
    const int bid = blockIdx.x;
    const int gtid = (bid << 9) + tid;

    for (int i = gtid; i < BB * HH; i += 131072) { h2a[i] = 0u; c2a[i] = 0u; }
    for (int i = gtid; i < BB * SS; i += 131072) {
        int b = i >> 9, s = i & 511;
        tsT[s * BB + b] = ts[i];
    }
    if (gtid < 1024) barv[gtid] = 0u;
    grid.sync();

    // XCD-aware bijective relabeling (L2 affinity for the 4 cgi slices/XCD)
    const int xcd = bid & 7, tt = bid >> 3;
    const int cgi = (xcd << 2) | (tt & 3);   // 0..31 -> m0
    const int rg  = tt >> 2;                 // 0..7  -> r0 (sync group)
    const int r0  = rg << 5;
    const int m0  = cgi << 4;

    const int wid = tid >> 6, lane = tid & 63;
    const int lrow = lane & 15, lk8 = lane >> 4;
    const int kq = wid & 3, ch = wid >> 2;
    const int rl = tid >> 4, mj = tid & 15;   // reduce/update mapping

    // LDS: partials only (49KB)
    __shared__ __align__(16) unsigned R2[12416];
    float* gp  = (float*)R2;              // [32][4][64] hashed
    float* gp2 = (float*)(R2 + 8192);     // [32][132]

    unsigned* arr = barv;                 // per-rg counter at barv[rg*64]
    const int myline = rg << 6;

    // register-resident: W frags + Wd frags
    bf16x8 wfh[4][2], wfl[4][2], d2h[2], d2l[2];
#pragma unroll
    for (int q = 0; q < 4; ++q)
#pragma unroll
        for (int wcl = 0; wcl < 2; ++wcl) {
            wfh[q][wcl] = B1FRAG((kq << 2) + q, (ch << 1) + wcl, 0);
            wfl[q][wcl] = B1FRAG((kq << 2) + q, (ch << 1) + wcl, 1);
        }
#pragma unroll
    for (int e = 0; e < 2; ++e) {
        d2h[e] = B2FRAG((wid << 1) + e, 0);
        d2l[e] = B2FRAG((wid << 1) + e, 1);
    }

    float bias4[4];
#pragma unroll
    for (int k = 0; k < 4; ++k)
        bias4[k] = ball[(k << 9) + m0 + mj] + bu[(k << 9) + m0 + mj];
    const float bias2v = bd[m0 + mj];

    // per-lane fragment element offsets
    const size_t xoff0 = (size_t)(r0 + lrow) * (SS * EE) + (kq << 7) + (lk8 << 3);
    const size_t xoff1 = xoff0 + (size_t)16 * (SS * EE);
    const int hoff0 = (r0 + lrow) * HH + (kq << 7) + (lk8 << 3);
    const int hoff1 = hoff0 + 16 * HH;
    const int coff0 = (r0 + lrow) * HH + (wid << 6) + (lk8 << 3);
    const int coff1 = coff0 + 16 * HH;

    float creg = 0.f, hsreg = 0.f;

#pragma unroll 1
    for (int s = 0; s < SS; ++s) {
        const unsigned* h2p = (s & 1) ? h2b : h2a;
        const unsigned* c2p = (s & 1) ? c2b : c2a;
        unsigned* h2n = (s & 1) ? h2a : h2b;
        unsigned* c2n = (s & 1) ? c2a : c2b;
        const size_t sb = (size_t)s * EE;

        // ---- phase A: x fragments, depth-2 pipeline + x.U MFMAs ----
        f32x4 acc[2][2];
        acc[0][0] = acc[0][1] = acc[1][0] = acc[1][1] = (f32x4){0.f, 0.f, 0.f, 0.f};
        {
            uint4 xq[2][2][2];
            bf16x8 ufh[2][2], ufl[2][2];
#pragma unroll
            for (int wcl = 0; wcl < 2; ++wcl) {
                ufh[0][wcl] = B1FRAG(16 + (kq << 2), (ch << 1) + wcl, 0);
                ufl[0][wcl] = B1FRAG(16 + (kq << 2), (ch << 1) + wcl, 1);
            }

#define PHA_Q(B, cur)                                                          \
            { _Pragma("unroll")                                                \
              for (int wr = 0; wr < 2; ++wr) {                                 \
                  bf16x8 ah = unhi(xq[B][wr][0], xq[B][wr][1]);                \
                  bf16x8 al = unlo(xq[B][wr][0], xq[B][wr][1]);                \
                  _Pragma("unroll")                                            \
                  for (int wcl = 0; wcl < 2; ++wcl) {                          \
                      acc[wr][wcl] = MF(ah, ufh[cur][wcl], acc[wr][wcl]);      \
                      acc[wr][wcl] = MF(ah, ufl[cur][wcl], acc[wr][wcl]);      \
                      acc[wr][wcl] = MF(al, ufh[cur][wcl], acc[wr][wcl]);      \
                  }                                                            \
              } }

            if (use_xp) {
                const unsigned* p0 = xp + xoff0 + sb;
                const unsigned* p1 = xp + xoff1 + sb;
#define ISSUE_X(B, Q)                                                          \
                ld4_nt(xq[B][0][0], p0 + ((Q) << 5));                          \
                ld4_nt(xq[B][0][1], p0 + ((Q) << 5) + 4);                      \
                ld4_nt(xq[B][1][0], p1 + ((Q) << 5));                          \
                ld4_nt(xq[B][1][1], p1 + ((Q) << 5) + 4);
                ISSUE_X(0, 0); ISSUE_X(1, 1);
#pragma unroll
                for (int q = 0; q < 4; ++q) {
                    const int cur = q & 1, nxt = cur ^ 1;
                    if (q < 3) {
#pragma unroll
                        for (int wcl = 0; wcl < 2; ++wcl) {
                            ufh[nxt][wcl] = B1FRAG(16 + (kq << 2) + q + 1, (ch << 1) + wcl, 0);
                            ufl[nxt][wcl] = B1FRAG(16 + (kq << 2) + q + 1, (ch << 1) + wcl, 1);
                        }
                        VMW(4);
                    } else {
                        VMW(0);
                    }
                    if (q == 0) { PHA_Q(0, 0); ISSUE_X(0, 2); }
                    else if (q == 1) { PHA_Q(1, 1); ISSUE_X(1, 3); }
                    else if (q == 2) { PHA_Q(0, 0); }
                    else { PHA_Q(1, 1); }
                }
            } else {
                const float* f0 = x + xoff0 + sb;
                const float* f1 = x + xoff1 + sb;
#pragma unroll
                for (int q = 0; q < 4; ++q) {
                    const int cur = q & 1, nxt = cur ^ 1;
                    if (q < 3) {
#pragma unroll
                        for (int wcl = 0; wcl < 2; ++wcl) {
                            ufh[nxt][wcl] = B1FRAG(16 + (kq << 2) + q + 1, (ch << 1) + wcl, 0);
                            ufl[nxt][wcl] = B1FRAG(16 + (kq << 2) + q + 1, (ch << 1) + wcl, 1);
                        }
                    }
#pragma unroll
                    for (int wr = 0; wr < 2; ++wr) {
                        const float* fp = wr ? f1 : f0;
                        float4 a = *(const float4*)(fp + (q << 5));
                        float4 b = *(const float4*)(fp + (q << 5) + 4);
                        xq[cur][wr][0] = (uint4){packsplit(a.x), packsplit(a.y),
                                                 packsplit(a.z), packsplit(a.w)};
                        xq[cur][wr][1] = (uint4){packsplit(b.x), packsplit(b.y),
                                                 packsplit(b.z), packsplit(b.w)};
                    }
                    if (q == 0) { PHA_Q(0, 0); }
                    else if (q == 1) { PHA_Q(1, 1); }
                    else if (q == 2) { PHA_Q(0, 0); }
                    else { PHA_Q(1, 1); }
                }
            }
        }

        // ---- B: per-rg wait (all 32 same-rg blocks finished step s-1) ----
        if (tid == 0) {
            const unsigned tgt = 32u * (unsigned)s;
            while (ld_devu(&arr[myline]) < tgt)
                __builtin_amdgcn_s_sleep(4);
        }
        __syncthreads();
        asm volatile("" ::: "memory");

        // ---- phase B: h fragments depth-2 (sc1) + h.W MFMA; then G2 ----
        f32x4 acc2[2];
        acc2[0] = (f32x4){0.f, 0.f, 0.f, 0.f};
        acc2[1] = (f32x4){0.f, 0.f, 0.f, 0.f};
        {
            uint4 hq[2][2][2], cq[2][2][2];
            const unsigned* hp0 = h2p + hoff0;
            const unsigned* hp1 = h2p + hoff1;
            const unsigned* cp0 = c2p + coff0;
            const unsigned* cp1 = c2p + coff1;

#define ISSUE_H(B, Q)                                                          \
            ld4_sc1(hq[B][0][0], hp0 + ((Q) << 5));                            \
            ld4_sc1(hq[B][0][1], hp0 + ((Q) << 5) + 4);                        \
            ld4_sc1(hq[B][1][0], hp1 + ((Q) << 5));                            \
            ld4_sc1(hq[B][1][1], hp1 + ((Q) << 5) + 4);
#define ISSUE_C(B, E)                                                          \
            ld4_sc1(cq[B][0][0], cp0 + ((E) << 5));                            \
            ld4_sc1(cq[B][0][1], cp0 + ((E) << 5) + 4);                        \
            ld4_sc1(cq[B][1][0], cp1 + ((E) << 5));                            \
            ld4_sc1(cq[B][1][1], cp1 + ((E) << 5) + 4);
#define PHB_Q(B, q)                                                            \
            { _Pragma("unroll")                                                \
              for (int wr = 0; wr < 2; ++wr) {                                 \
                  bf16x8 ah = unhi(hq[B][wr][0], hq[B][wr][1]);                \
                  bf16x8 al = unlo(hq[B][wr][0], hq[B][wr][1]);                \
                  _Pragma("unroll")                                            \
                  for (int wcl = 0; wcl < 2; ++wcl) {                          \
                      acc[wr][wcl] = MF(ah, wfh[q][wcl], acc[wr][wcl]);        \
                      acc[wr][wcl] = MF(ah, wfl[q][wcl], acc[wr][wcl]);        \
                      acc[wr][wcl] = MF(al, wfh[q][wcl], acc[wr][wcl]);        \
                  }                                                            \
              } }
#define G2_E(B, e)                                                             \
            { _Pragma("unroll")                                                \
              for (int wr = 0; wr < 2; ++wr) {                                 \
                  bf16x8 ah = unhi(cq[B][wr][0], cq[B][wr][1]);                \
                  bf16x8 al = unlo(cq[B][wr][0], cq[B][wr][1]);                \
                  acc2[wr] = MF(ah, d2h[e], acc2[wr]);                         \
                  acc2[wr] = MF(ah, d2l[e], acc2[wr]);                         \
                  acc2[wr] = MF(al, d2h[e], acc2[wr]);                         \
              } }

            ISSUE_H(0, 0); ISSUE_H(1, 1);
            VMW(4); PHB_Q(0, 0); ISSUE_H(0, 2);
            VMW(4); PHB_Q(1, 1); ISSUE_H(1, 3);
            VMW(4); PHB_Q(0, 2); ISSUE_C(0, 0); ISSUE_C(1, 1);
            VMW(8); PHB_Q(1, 3);
            VMW(4); G2_E(0, 0);
            VMW(0); G2_E(1, 1);
        }

        // ---- E: partial writes (gp: slot=kq; gp2: slot=wid) ----
        __syncthreads();                     // prev reduce reads of R2 done
#pragma unroll
        for (int wr = 0; wr < 2; ++wr)
#pragma unroll
            for (int wcl = 0; wcl < 2; ++wcl)
#pragma unroll
                for (int i = 0; i < 4; ++i)
                    gp[GPIDX((wr << 4) + (lk8 << 2) + i, kq, ((ch << 1) + wcl) * 16 + lrow)] = acc[wr][wcl][i];
#pragma unroll
        for (int wr = 0; wr < 2; ++wr)
#pragma unroll
            for (int i = 0; i < 4; ++i)
                gp2[((wr << 4) + (lk8 << 2) + i) * 132 + (wid << 4) + lrow] = acc2[wr][i];
        __syncthreads();

        // ---- F: reduce + update + sc1 stores ----
        {
            float gv[4];
#pragma unroll
            for (int k = 0; k < 4; ++k) {
                float sacc = bias4[k];
#pragma unroll
                for (int p = 0; p < 4; ++p)
                    sacc += gp[GPIDX(rl, p, (k << 4) + mj)];
                gv[k] = my_sig(sacc);
            }
            float sacc2 = bias2v;
#pragma unroll
            for (int p = 0; p < 8; ++p)
                sacc2 += gp2[rl * 132 + (p << 4) + mj];
            const float cs1v = my_tanh(sacc2);
            const float tv = tsT[s * BB + r0 + rl];
            const float cadj = creg + cs1v * (tv - 1.0f);
            const float cnew = gv[0] * cadj + gv[1] * gv[3];
            const float hnew = gv[2] * my_tanh(cnew);
            creg = cnew; hsreg += hnew;
            const int gidx = (r0 + rl) * HH + m0 + mj;
            st_devu(&c2n[gidx], packsplit(cnew));
            st_devu(&h2n[gidx], packsplit(hnew));
        }

        // ---- G: drain + per-rg arrival ----
        asm volatile("s_waitcnt vmcnt(0)" ::: "memory");
        __syncthreads();
        if (tid == 0)
            __hip_atomic_fetch_add(&arr[myline], 1u, __ATOMIC_RELAXED,
                                   __HIP_MEMORY_SCOPE_AGENT);
    }

    hsum[(r0 + rl) * HH + m0 + mj] = hsreg;
}

// Tail: sub = relu(tfidf@fcw+b); x = [sub | hsum/512]; 3-layer MLP (fp32).
__global__ void __launch_bounds__(256)
tail_kernel(const float* __restrict__ tfidf, const float* __restrict__ hsum,
            const float* __restrict__ fcw, const float* __restrict__ fcb,
            const float* __restrict__ l1w, const float* __restrict__ l1b,
            const float* __restrict__ l2w, const float* __restrict__ l2b,
            const float* __restrict__ low, const float* __restrict__ lob,
            float* __restrict__ out)
{
    const int row = blockIdx.x;
    const int t = threadIdx.x;
    __shared__ float tf[800];
    __shared__ float xrow[1024];
    __shared__ float y1[256];
    __shared__ float y2[128];

    for (int k = t; k < NTF; k += 256) tf[k] = tfidf[row * NTF + k];
    __syncthreads();

    for (int n = t; n < 512; n += 256) {
        float acc = fcb[n];
        for (int k = 0; k < NTF; ++k) acc += tf[k] * fcw[k * 512 + n];
        xrow[n] = fmaxf(acc, 0.f);
    }
    for (int n = t; n < 512; n += 256)
        xrow[512 + n] = hsum[row * HH + n] * (1.0f / 512.0f);
    __syncthreads();

    {
        float acc = l1b[t];
        for (int k = 0; k < 1024; ++k) acc += xrow[k] * l1w[k * 256 + t];
        y1[t] = fmaxf(acc, 0.f);
    }
    __syncthreads();
    if (t < 128) {
        float acc = l2b[t];
        for (int k = 0; k < 256; ++k) acc += y1[k] * l2w[k * 128 + t];
        y2[t] = fmaxf(acc, 0.f);
    }
    __syncthreads();
    if (t < 2) {
        float acc = lob[t];
        for (int k = 0; k < 128; ++k) acc += y2[k] * low[k * 2 + t];
        out[row * 2 + t] = acc;
    }
}

extern "C" void kernel_launch(void* const* d_in, const int* in_sizes, int n_in,
                              void* d_out, int out_size, void* d_ws, size_t ws_size,
                              hipStream_t stream)
{
    const float* x     = (const float*)d_in[0];
    const float* ts    = (const float*)d_in[1];
    const float* tfidf = (const float*)d_in[2];
    const float* Wall  = (const float*)d_in[3];
    const float* ball  = (const float*)d_in[4];
    const float* Uall  = (const float*)d_in[5];
    const float* bu    = (const float*)d_in[6];
    const float* Wd    = (const float*)d_in[7];
    const float* bd    = (const float*)d_in[8];
    const float* fcw   = (const float*)d_in[9];
    const float* fcb   = (const float*)d_in[10];
    const float* l1w   = (const float*)d_in[11];
    const float* l1b   = (const float*)d_in[12];
    const float* l2w   = (const float*)d_in[13];
    const float* l2b   = (const float*)d_in[14];
    const float* low   = (const float*)d_in[15];
    const float* lob   = (const float*)d_in[16];
    float* out = (float*)d_out;

    unsigned* wsu = (unsigned*)d_ws;
    unsigned* h2a = wsu;
    unsigned* h2b = h2a + BB * HH;
    unsigned* c2a = h2b + BB * HH;
    unsigned* c2b = c2a + BB * HH;
    float* hs  = (float*)(c2b + BB * HH);
    float* tsT = hs + BB * HH;
    unsigned* barv = (unsigned*)(tsT + BB * SS);               // 1024 u32
    unsigned short* B1 = (unsigned short*)(barv + 1024);
    unsigned short* B2 = B1 + (size_t)32 * 32 * 4 * 2 * 64 * 8;   // B1 = 16.8MB
    unsigned* xpk = (unsigned*)(B2 + (size_t)32 * 16 * 2 * 64 * 8); // after 1MB B2
    const size_t need = ((char*)(xpk + (size_t)BB * SS * EE)) - (char*)d_ws;
    const int use_xp = (ws_size >= need) ? 1 : 0;

    prep_split<<<1152, 256, 0, stream>>>(Wall, Uall, Wd, B1, B2);
    if (use_xp)
        prep_pack<<<65536, 256, 0, stream>>>(x, xpk);

    void* args[] = { (void*)&x, (void*)&xpk, (void*)&use_xp, (void*)&ts,
                     (void*)&ball, (void*)&bu, (void*)&bd,
                     (void*)&B1, (void*)&B2,
                     (void*)&h2a, (void*)&h2b, (void*)&c2a, (void*)&c2b,
                     (void*)&hs, (void*)&tsT, (void*)&barv };
    hipLaunchCooperativeKernel((void*)lstm_persistent, dim3(256), dim3(512), args, 0, stream);

    tail_kernel<<<256, 256, 0, stream>>>(tfidf, hs, fcw, fcb, l1w, l1b, l2w, l2b,
                                         low, lob, out);
}

// Round 16
// 6332.051 us; speedup vs baseline: 1.1697x; 1.1697x over previous
//
#include <hip/hip_runtime.h>
#include <hip/hip_cooperative_groups.h>

namespace cg = cooperative_groups;

#define BB 256
#define SS 512
#define EE 512
#define HH 512
#define G4 2048
#define NTF 799
#define U4PB (512 * 2048)   // floats of u per (rg,cgi) tile

typedef __attribute__((ext_vector_type(8))) short bf16x8;
typedef __attribute__((ext_vector_type(4))) float f32x4;

#define MF(a, b, c) __builtin_amdgcn_mfma_f32_16x16x32_bf16((a), (b), (c), 0, 0, 0)

__device__ __forceinline__ float my_sig(float v) { return 1.0f / (1.0f + __expf(-v)); }
__device__ __forceinline__ float my_tanh(float v) { float e = __expf(2.0f * v); return 1.0f - 2.0f / (e + 1.0f); }

__device__ __forceinline__ unsigned short f2bf(float f) {   // RNE fp32->bf16
    unsigned u = __builtin_bit_cast(unsigned, f);
    u = (u + 0x7FFFu + ((u >> 16) & 1u)) >> 16;
    return (unsigned short)u;
}
__device__ __forceinline__ float bf2f(unsigned short h) {
    unsigned u = ((unsigned)h) << 16;
    return __builtin_bit_cast(float, u);
}
__device__ __forceinline__ unsigned packsplit(float f) {
    unsigned short hi = f2bf(f);
    unsigned short lo = f2bf(f - bf2f(hi));
    return ((unsigned)hi << 16) | (unsigned)lo;
}
__device__ __forceinline__ bf16x8 unhi(uint4 a, uint4 b) {
    union { unsigned u[4]; bf16x8 v; } r;
    r.u[0] = __builtin_amdgcn_perm(a.y, a.x, 0x07060302u);
    r.u[1] = __builtin_amdgcn_perm(a.w, a.z, 0x07060302u);
    r.u[2] = __builtin_amdgcn_perm(b.y, b.x, 0x07060302u);
    r.u[3] = __builtin_amdgcn_perm(b.w, b.z, 0x07060302u);
    return r.v;
}
__device__ __forceinline__ bf16x8 unlo(uint4 a, uint4 b) {
    union { unsigned u[4]; bf16x8 v; } r;
    r.u[0] = __builtin_amdgcn_perm(a.y, a.x, 0x05040100u);
    r.u[1] = __builtin_amdgcn_perm(a.w, a.z, 0x05040100u);
    r.u[2] = __builtin_amdgcn_perm(b.y, b.x, 0x05040100u);
    r.u[3] = __builtin_amdgcn_perm(b.w, b.z, 0x05040100u);
    return r.v;
}

// sc1 coherent / nt streaming accesses (verified r4-r12)
__device__ __forceinline__ void ld4_sc1(uint4& d, const unsigned* p) {
    asm volatile("global_load_dwordx4 %0, %1, off sc0 sc1" : "=v"(d) : "v"(p));
}
__device__ __forceinline__ void ld4_nt(uint4& d, const unsigned* p) {
    asm volatile("global_load_dwordx4 %0, %1, off nt" : "=v"(d) : "v"(p));
}
__device__ __forceinline__ void st_devu(unsigned* p, unsigned v) {
    __hip_atomic_store(p, v, __ATOMIC_RELAXED, __HIP_MEMORY_SCOPE_AGENT);
}
__device__ __forceinline__ unsigned ld_devu(const unsigned* p) {
    return __hip_atomic_load(p, __ATOMIC_RELAXED, __HIP_MEMORY_SCOPE_AGENT);
}

// ---------------------------------------------------------------------------
// Prep: split weights into bf16 hi/lo MFMA B-fragments (verbatim r8-r12).
// ---------------------------------------------------------------------------
__global__ void __launch_bounds__(256)
prep_split(const float* __restrict__ Wall, const float* __restrict__ Uall,
           const float* __restrict__ Wd,
           unsigned short* __restrict__ B1, unsigned short* __restrict__ B2)
{
    const int t = blockIdx.x * 256 + threadIdx.x;
    if (t < 262144) {
        const int lane = t & 63, wc = (t >> 6) & 3, kc = (t >> 8) & 31, cgi = t >> 13;
        const int kb = ((kc & 15) << 5) + ((lane >> 4) << 3);
        const int col = (wc << 9) + (cgi << 4) + (lane & 15);
        const float* src = (kc < 16) ? Wall : Uall;
        bf16x8 vh, vl;
#pragma unroll
        for (int j = 0; j < 8; ++j) {
            float f = src[(size_t)(kb + j) * G4 + col];
            unsigned short h16 = f2bf(f);
            vh[j] = (short)h16;
            vl[j] = (short)f2bf(f - bf2f(h16));
        }
        const int g = t >> 6;
        *(bf16x8*)(B1 + ((size_t)(g * 2 + 0) * 64 + lane) * 8) = vh;
        *(bf16x8*)(B1 + ((size_t)(g * 2 + 1) * 64 + lane) * 8) = vl;
    } else if (t < 262144 + 32768) {
        const int u = t - 262144;
        const int lane = u & 63, kch = (u >> 6) & 15, cgi = u >> 10;
        const int kb = (kch << 5) + ((lane >> 4) << 3);
        const int col = (cgi << 4) + (lane & 15);
        bf16x8 vh, vl;
#pragma unroll
        for (int j = 0; j < 8; ++j) {
            float f = Wd[(size_t)(kb + j) * HH + col];
            unsigned short h16 = f2bf(f);
            vh[j] = (short)h16;
            vl[j] = (short)f2bf(f - bf2f(h16));
        }
        const int g = u >> 6;
        *(bf16x8*)(B2 + ((size_t)(g * 2 + 0) * 64 + lane) * 8) = vh;
        *(bf16x8*)(B2 + ((size_t)(g * 2 + 1) * 64 + lane) * 8) = vl;
    }
}

// Prep: pack x -> hi|lo u32 (fallback path only)
__global__ void __launch_bounds__(256)
prep_pack(const float* __restrict__ x, unsigned* __restrict__ xpk)
{
    const size_t i = (size_t)blockIdx.x * 256 + threadIdx.x;   // 16.7M float4s
    float4 v = ((const float4*)x)[i];
    uint4 p;
    p.x = packsplit(v.x); p.y = packsplit(v.y);
    p.z = packsplit(v.z); p.w = packsplit(v.w);
    ((uint4*)xpk)[i] = p;
}

#define B1FRAG(kcv, wcv, term) (*(const bf16x8*)(B1 +                          \
    ((size_t)(((cgi * 32 + (kcv)) * 4 + (wcv)) * 2 + (term)) * 64 + lane) * 8))
#define B2FRAG(kchv, term) (*(const bf16x8*)(B2 +                              \
    ((size_t)((cgi * 16 + (kchv)) * 2 + (term)) * 64 + lane) * 8))

// gate-partial LDS index, bank-hashed (2-way max = free)
#define GPIDX(row, slot, col)                                                  \
    ((row) * 256 + (slot) * 64 + ((col) ^ (((((row) & 3) ^ (((row) >> 2) & 3))) << 4)))

// ---------------------------------------------------------------------------
// u_gemm: u[bl][s][4][32][16] = x(s) @ Uall for tile bl=(rg,cgi). No barriers,
// fully parallel over (bl, s-half). Reuses r12's verified phase-A staging +
// MFMA code. 512 blocks x 512 threads, 64KB LDS (AX then partials).
// ---------------------------------------------------------------------------
__global__ void __launch_bounds__(512) __attribute__((amdgpu_waves_per_eu(4)))
u_gemm(const float* __restrict__ x, const unsigned* __restrict__ xp,
       const int use_xp, const unsigned short* __restrict__ B1,
       float* __restrict__ uall)
{
    const int tid = threadIdx.x;
    const int b = blockIdx.x;
    const int bl = b >> 1;
    const int s0 = (b & 1) << 8;          // 0 or 256
    const int rg = bl >> 5, cgi = bl & 31;
    const int r0 = rg << 5;

    const int wid = tid >> 6, lane = tid & 63;
    const int lrow = lane & 15, lk8 = lane >> 4;
    const int kq = wid & 3, ch = wid >> 2;
    const int srow = tid >> 4, scb = tid & 15;
    const int rl = srow, mj = scb;

    __shared__ __align__(16) unsigned R1[32 * 512];   // AX, then gate partials
    uint4* R1v = (uint4*)R1;
    float* gp = (float*)R1;

    float* ub = uall + (size_t)bl * U4PB;

#pragma unroll 1
    for (int s = s0; s < s0 + 256; ++s) {
        const size_t sb = (size_t)s * EE;
        __syncthreads();                  // prev reduce reads of gp done
        if (use_xp) {
            const unsigned* xpp = xp + (size_t)(r0 + srow) * (SS * EE) + sb;
            uint4 xv[8];
#pragma unroll
            for (int j = 0; j < 8; ++j) ld4_nt(xv[j], xpp + ((scb + (j << 4)) << 2));
            asm volatile("s_waitcnt vmcnt(0)" ::: "memory");
            __builtin_amdgcn_sched_barrier(0);
#pragma unroll
            for (int j = 0; j < 8; ++j) {
                const int ci = scb + (j << 4);
                R1v[srow * 128 + (ci ^ (srow & 7))] = xv[j];
            }
        } else {
            const float* xfp = x + (size_t)(r0 + srow) * (SS * EE) + sb;
#pragma unroll
            for (int j = 0; j < 8; ++j) {
                const int ci = scb + (j << 4);
                float4 v = *(const float4*)(xfp + (ci << 2));
                uint4 pk;
                pk.x = packsplit(v.x); pk.y = packsplit(v.y);
                pk.z = packsplit(v.z); pk.w = packsplit(v.w);
                R1v[srow * 128 + (ci ^ (srow & 7))] = pk;
            }
        }
        __syncthreads();

        // x.U MFMAs, U frags streamed double-buffered (r12 phase A verbatim)
        f32x4 acc[2][2];
        acc[0][0] = acc[0][1] = acc[1][0] = acc[1][1] = (f32x4){0.f, 0.f, 0.f, 0.f};
        {
            bf16x8 ufh[2][2], ufl[2][2];
#pragma unroll
            for (int wcl = 0; wcl < 2; ++wcl) {
                ufh[0][wcl] = B1FRAG(16 + (kq << 2), (ch << 1) + wcl, 0);
                ufl[0][wcl] = B1FRAG(16 + (kq << 2), (ch << 1) + wcl, 1);
            }
#pragma unroll
            for (int q = 0; q < 4; ++q) {
                const int cur = q & 1, nxt = cur ^ 1;
                if (q < 3) {
#pragma unroll
                    for (int wcl = 0; wcl < 2; ++wcl) {
                        ufh[nxt][wcl] = B1FRAG(16 + (kq << 2) + q + 1, (ch << 1) + wcl, 0);
                        ufl[nxt][wcl] = B1FRAG(16 + (kq << 2) + q + 1, (ch << 1) + wcl, 1);
                    }
                }
                const int kcp = (kq << 2) + q;
#pragma unroll
                for (int wr = 0; wr < 2; ++wr) {
                    const int row_ = (wr << 4) | lrow;
                    const int cb_  = (kcp << 3) + (lk8 << 1);
                    uint4 qa = R1v[row_ * 128 + (cb_ ^ (row_ & 7))];
                    uint4 qb = R1v[row_ * 128 + ((cb_ + 1) ^ (row_ & 7))];
                    bf16x8 ah = unhi(qa, qb), al = unlo(qa, qb);
#pragma unroll
                    for (int wcl = 0; wcl < 2; ++wcl) {
                        acc[wr][wcl] = MF(ah, ufh[cur][wcl], acc[wr][wcl]);
                        acc[wr][wcl] = MF(ah, ufl[cur][wcl], acc[wr][wcl]);
                        acc[wr][wcl] = MF(al, ufh[cur][wcl], acc[wr][wcl]);
                    }
                }
            }
        }
        __syncthreads();                  // all MFMA reads of R1 done

        // partial writes (slot = kq) into R1's gp region
#pragma unroll
        for (int wr = 0; wr < 2; ++wr)
#pragma unroll
            for (int wcl = 0; wcl < 2; ++wcl)
#pragma unroll
                for (int i = 0; i < 4; ++i)
                    gp[GPIDX((wr << 4) + (lk8 << 2) + i, kq, ((ch << 1) + wcl) * 16 + lrow)] = acc[wr][wcl][i];
        __syncthreads();

        // reduce over 4 slots + nt store u[s][k][rl][mj]
        {
            float* up = ub + (size_t)s * 2048 + (rl << 4) + mj;
#pragma unroll
            for (int k = 0; k < 4; ++k) {
                float sacc = 0.f;
#pragma unroll
                for (int p = 0; p < 4; ++p)
                    sacc += gp[GPIDX(rl, p, (k << 4) + mj)];
                __builtin_nontemporal_store(sacc, up + (k << 9));
            }
        }
    }
}

// ---------------------------------------------------------------------------
// Persistent time-LSTM (r12 structure verbatim; 4.94ms verified). u-mode:
// phase A replaced by 4 nt loads of the precomputed u slice (issued before
// the barrier poll); reduce adds bias+u+h-partials. Fallback = exact r12.
// ---------------------------------------------------------------------------
__global__ void __launch_bounds__(512) __attribute__((amdgpu_waves_per_eu(2)))
lstm_persistent(const float* __restrict__ x, const unsigned* __restrict__ xp,
                const int use_xp, const float* __restrict__ ts,
                const float* __restrict__ ball, const float* __restrict__ bu,
                const float* __restrict__ bd,
                const unsigned short* __restrict__ B1,
                const unsigned short* __restrict__ B2,
                unsigned* __restrict__ h2a, unsigned* __restrict__ h2b,
                unsigned* __restrict__ c2a, unsigned* __restrict__ c2b,
                float* __restrict__ hsum, float* __restrict__ tsT,
                unsigned* __restrict__ barv,
                const float* __restrict__ uall, const int use_u)
{
    cg::grid_group grid = cg::this_grid();
    const int tid = threadIdx.x;
    const int bid = blockIdx.x;
    const int gtid = (bid << 9) + tid;

    for (int i = gtid; i < BB * HH; i += 131072) { h2a[i] = 0u; c2a[i] = 0u; }
    for (int i = gtid; i < BB * SS; i += 131072) {
        int b = i >> 9, s = i & 511;
        tsT[s * BB + b] = ts[i];
    }
    if (gtid < 1024) barv[gtid] = 0u;
    grid.sync();

    // XCD-aware bijective relabeling (L2 affinity for the 4 cgi slices/XCD)
    const int xcd = bid & 7, tt = bid >> 3;
    const int cgi = (xcd << 2) | (tt & 3);   // 0..31 -> m0
    const int rg  = tt >> 2;                 // 0..7  -> r0 (sync group)
    const int r0  = rg << 5;
    const int m0  = cgi << 4;
    const int bl  = (rg << 5) | cgi;

    const int wid = tid >> 6, lane = tid & 63;
    const int lrow = lane & 15, lk8 = lane >> 4;
    const int kq = wid & 3, ch = wid >> 2;
    const int srow = tid >> 4, scb = tid & 15;
    const int rl = srow, mj = scb;

    __shared__ __align__(16) unsigned R1[32 * 512];  // AX -> AC
    __shared__ __align__(16) unsigned R2[32 * 512];  // AH -> partials
    uint4* R1v = (uint4*)R1;
    uint4* R2v = (uint4*)R2;
    float* gp  = (float*)R2;              // [32][4][64] hashed, 32KB
    float* gp2 = (float*)(R2 + 8192);     // [32][132], 17KB

    unsigned* arr = barv;                 // per-rg counter at barv[rg*64]
    const int myline = rg << 6;

    // register-resident: W frags + Wd frags
    bf16x8 wfh[4][2], wfl[4][2], d2h[2], d2l[2];
#pragma unroll
    for (int q = 0; q < 4; ++q)
#pragma unroll
        for (int wcl = 0; wcl < 2; ++wcl) {
            wfh[q][wcl] = B1FRAG((kq << 2) + q, (ch << 1) + wcl, 0);
            wfl[q][wcl] = B1FRAG((kq << 2) + q, (ch << 1) + wcl, 1);
        }
#pragma unroll
    for (int e = 0; e < 2; ++e) {
        d2h[e] = B2FRAG((wid << 1) + e, 0);
        d2l[e] = B2FRAG((wid << 1) + e, 1);
    }

    float bias4[4];
#pragma unroll
    for (int k = 0; k < 4; ++k)
        bias4[k] = ball[(k << 9) + m0 + mj] + bu[(k << 9) + m0 + mj];
    const float bias2v = bd[m0 + mj];

    const float* ubase = uall + (size_t)bl * U4PB + (rl << 4) + mj;

    float creg = 0.f, hsreg = 0.f;

#pragma unroll 1
    for (int s = 0; s < SS; ++s) {
        const unsigned* h2p = (s & 1) ? h2b : h2a;
        const unsigned* c2p = (s & 1) ? c2b : c2a;
        unsigned* h2n = (s & 1) ? h2a : h2b;
        unsigned* c2n = (s & 1) ? c2a : c2b;
        const size_t sb = (size_t)s * EE;

        float uv[4] = {0.f, 0.f, 0.f, 0.f};
        f32x4 acc[2][2];
        acc[0][0] = acc[0][1] = acc[1][0] = acc[1][1] = (f32x4){0.f, 0.f, 0.f, 0.f};

        if (use_u) {
            // u-mode: issue u-slice loads (hidden under the barrier wait)
            const float* up = ubase + (size_t)s * 2048;
            uv[0] = __builtin_nontemporal_load(up);
            uv[1] = __builtin_nontemporal_load(up + 512);
            uv[2] = __builtin_nontemporal_load(up + 1024);
            uv[3] = __builtin_nontemporal_load(up + 1536);
        } else {
            // ---- fallback phase A: stage AX <- x(s) + x.U MFMAs (r12) ----
            __syncthreads();
            if (use_xp) {
                const unsigned* xpp = xp + (size_t)(r0 + srow) * (SS * EE) + sb;
                uint4 xv[8];
#pragma unroll
                for (int j = 0; j < 8; ++j) ld4_nt(xv[j], xpp + ((scb + (j << 4)) << 2));
                asm volatile("s_waitcnt vmcnt(0)" ::: "memory");
                __builtin_amdgcn_sched_barrier(0);
#pragma unroll
                for (int j = 0; j < 8; ++j) {
                    const int ci = scb + (j << 4);
                    R1v[srow * 128 + (ci ^ (srow & 7))] = xv[j];
                }
            } else {
                const float* xfp = x + (size_t)(r0 + srow) * (SS * EE) + sb;
#pragma unroll
                for (int j = 0; j < 8; ++j) {
                    const int ci = scb + (j << 4);
                    float4 v = *(const float4*)(xfp + (ci << 2));
                    uint4 pk;
                    pk.x = packsplit(v.x); pk.y = packsplit(v.y);
                    pk.z = packsplit(v.z); pk.w = packsplit(v.w);
                    R1v[srow * 128 + (ci ^ (srow & 7))] = pk;
                }
            }
            __syncthreads();
            {
                bf16x8 ufh[2][2], ufl[2][2];
#pragma unroll
                for (int wcl = 0; wcl < 2; ++wcl) {
                    ufh[0][wcl] = B1FRAG(16 + (kq << 2), (ch << 1) + wcl, 0);
                    ufl[0][wcl] = B1FRAG(16 + (kq << 2), (ch << 1) + wcl, 1);
                }
#pragma unroll
                for (int q = 0; q < 4; ++q) {
                    const int cur = q & 1, nxt = cur ^ 1;
                    if (q < 3) {
#pragma unroll
                        for (int wcl = 0; wcl < 2; ++wcl) {
                            ufh[nxt][wcl] = B1FRAG(16 + (kq << 2) + q + 1, (ch << 1) + wcl, 0);
                            ufl[nxt][wcl] = B1FRAG(16 + (kq << 2) + q + 1, (ch << 1) + wcl, 1);
                        }
                    }
                    const int kcp = (kq << 2) + q;
#pragma unroll
                    for (int wr = 0; wr < 2; ++wr) {
                        const int row_ = (wr << 4) | lrow;
                        const int cb_  = (kcp << 3) + (lk8 << 1);
                        uint4 qa = R1v[row_ * 128 + (cb_ ^ (row_ & 7))];
                        uint4 qb = R1v[row_ * 128 + ((cb_ + 1) ^ (row_ & 7))];
                        bf16x8 ah = unhi(qa, qb), al = unlo(qa, qb);
#pragma unroll
                        for (int wcl = 0; wcl < 2; ++wcl) {
                            acc[wr][wcl] = MF(ah, ufh[cur][wcl], acc[wr][wcl]);
                            acc[wr][wcl] = MF(ah, ufl[cur][wcl], acc[wr][wcl]);
                            acc[wr][wcl] = MF(al, ufh[cur][wcl], acc[wr][wcl]);
                        }
                    }
                }
            }
        }

        // ---- B: per-rg wait (all 32 same-rg blocks finished step s-1) ----
        if (tid == 0) {
            const unsigned tgt = 32u * (unsigned)s;
            while (ld_devu(&arr[myline]) < tgt)
                __builtin_amdgcn_s_sleep(4);
        }
        __syncthreads();
        asm volatile("" ::: "memory");

        // ---- C: fused h+c load (16 dwordx4, vmcnt(8)/vmcnt(0) split) ----
        {
            const unsigned* hp = h2p + (r0 + srow) * HH;
            const unsigned* cp = c2p + (r0 + srow) * HH;
            uint4 hv[8], cv[8];
#pragma unroll
            for (int j = 0; j < 8; ++j) ld4_sc1(hv[j], hp + ((scb + (j << 4)) << 2));
#pragma unroll
            for (int j = 0; j < 8; ++j) ld4_sc1(cv[j], cp + ((scb + (j << 4)) << 2));
            asm volatile("s_waitcnt vmcnt(8)" ::: "memory");
            __builtin_amdgcn_sched_barrier(0);
#pragma unroll
            for (int j = 0; j < 8; ++j) {
                const int ci = scb + (j << 4);
                R2v[srow * 128 + (ci ^ (srow & 7))] = hv[j];
            }
            asm volatile("s_waitcnt vmcnt(0)" ::: "memory");
            __builtin_amdgcn_sched_barrier(0);
#pragma unroll
            for (int j = 0; j < 8; ++j) {
                const int ci = scb + (j << 4);
                R1v[srow * 128 + (ci ^ (srow & 7))] = cv[j];
            }
        }
        __syncthreads();

        // ---- phase B: h.W MFMAs into acc; then G2 (c.Wd) ----
#pragma unroll
        for (int q = 0; q < 4; ++q) {
            const int kcp = (kq << 2) + q;
#pragma unroll
            for (int wr = 0; wr < 2; ++wr) {
                const int row_ = (wr << 4) | lrow;
                const int cb_  = (kcp << 3) + (lk8 << 1);
                uint4 qa = R2v[row_ * 128 + (cb_ ^ (row_ & 7))];
                uint4 qb = R2v[row_ * 128 + ((cb_ + 1) ^ (row_ & 7))];
                bf16x8 ah = unhi(qa, qb), al = unlo(qa, qb);
#pragma unroll
                for (int wcl = 0; wcl < 2; ++wcl) {
                    acc[wr][wcl] = MF(ah, wfh[q][wcl], acc[wr][wcl]);
                    acc[wr][wcl] = MF(ah, wfl[q][wcl], acc[wr][wcl]);
                    acc[wr][wcl] = MF(al, wfh[q][wcl], acc[wr][wcl]);
                }
            }
        }
        f32x4 acc2[2];
        acc2[0] = (f32x4){0.f, 0.f, 0.f, 0.f};
        acc2[1] = (f32x4){0.f, 0.f, 0.f, 0.f};
#pragma unroll
        for (int e = 0; e < 2; ++e) {
            const int kch = (wid << 1) + e;
#pragma unroll
            for (int wr = 0; wr < 2; ++wr) {
                const int row_ = (wr << 4) | lrow;
                const int cb_  = (kch << 3) + (lk8 << 1);
                uint4 qa = R1v[row_ * 128 + (cb_ ^ (row_ & 7))];
                uint4 qb = R1v[row_ * 128 + ((cb_ + 1) ^ (row_ & 7))];
                bf16x8 ah = unhi(qa, qb), al = unlo(qa, qb);
                acc2[wr] = MF(ah, d2h[e], acc2[wr]);
                acc2[wr] = MF(ah, d2l[e], acc2[wr]);
                acc2[wr] = MF(al, d2h[e], acc2[wr]);
            }
        }
        __syncthreads();   // AH/AC reads done before partials overwrite R2

        // ---- E: partial writes (gp: slot=kq; gp2: slot=wid) ----
#pragma unroll
        for (int wr = 0; wr < 2; ++wr)
#pragma unroll
            for (int wcl = 0; wcl < 2; ++wcl)
#pragma unroll
                for (int i = 0; i < 4; ++i)
                    gp[GPIDX((wr << 4) + (lk8 << 2) + i, kq, ((ch << 1) + wcl) * 16 + lrow)] = acc[wr][wcl][i];
#pragma unroll
        for (int wr = 0; wr < 2; ++wr)
#pragma unroll
            for (int i = 0; i < 4; ++i)
                gp2[((wr << 4) + (lk8 << 2) + i) * 132 + (wid << 4) + lrow] = acc2[wr][i];
        __syncthreads();

        // ---- F: reduce (bias + u + partials) + update + sc1 stores ----
        {
            float gv[4];
#pragma unroll
            for (int k = 0; k < 4; ++k) {
                float sacc = bias4[k] + uv[k];
#pragma unroll
                for (int p = 0; p < 4; ++p)
                    sacc += gp[GPIDX(rl, p, (k << 4) + mj)];
                gv[k] = my_sig(sacc);
            }
            float sacc2 = bias2v;
#pragma unroll
            for (int p = 0; p < 8; ++p)
                sacc2 += gp2[rl * 132 + (p << 4) + mj];
            const float cs1v = my_tanh(sacc2);
            const float tv = tsT[s * BB + r0 + rl];
            const float cadj = creg + cs1v * (tv - 1.0f);
            const float cnew = gv[0] * cadj + gv[1] * gv[3];
            const float hnew = gv[2] * my_tanh(cnew);
            creg = cnew; hsreg += hnew;
            const int gidx = (r0 + rl) * HH + m0 + mj;
            st_devu(&c2n[gidx], packsplit(cnew));
            st_devu(&h2n[gidx], packsplit(hnew));
        }

        // ---- G: drain + per-rg arrival ----
        asm volatile("s_waitcnt vmcnt(0)" ::: "memory");
        __syncthreads();
        if (tid == 0)
            __hip_atomic_fetch_add(&arr[myline], 1u, __ATOMIC_RELAXED,
                                   __HIP_MEMORY_SCOPE_AGENT);
    }

    hsum[(r0 + rl) * HH + m0 + mj] = hsreg;
}

// Tail: sub = relu(tfidf@fcw+b); x = [sub | hsum/512]; 3-layer MLP (fp32).
__global__ void __launch_bounds__(256)
tail_kernel(const float* __restrict__ tfidf, const float* __restrict__ hsum,
            const float* __restrict__ fcw, const float* __restrict__ fcb,
            const float* __restrict__ l1w, const float* __restrict__ l1b,
            const float* __restrict__ l2w, const float* __restrict__ l2b,
            const float* __restrict__ low, const float* __restrict__ lob,
            float* __restrict__ out)
{
    const int row = blockIdx.x;
    const int t = threadIdx.x;
    __shared__ float tf[800];
    __shared__ float xrow[1024];
    __shared__ float y1[256];
    __shared__ float y2[128];

    for (int k = t; k < NTF; k += 256) tf[k] = tfidf[row * NTF + k];
    __syncthreads();

    for (int n = t; n < 512; n += 256) {
        float acc = fcb[n];
        for (int k = 0; k < NTF; ++k) acc += tf[k] * fcw[k * 512 + n];
        xrow[n] = fmaxf(acc, 0.f);
    }
    for (int n = t; n < 512; n += 256)
        xrow[512 + n] = hsum[row * HH + n] * (1.0f / 512.0f);
    __syncthreads();

    {
        float acc = l1b[t];
        for (int k = 0; k < 1024; ++k) acc += xrow[k] * l1w[k * 256 + t];
        y1[t] = fmaxf(acc, 0.f);
    }
    __syncthreads();
    if (t < 128) {
        float acc = l2b[t];
        for (int k = 0; k < 256; ++k) acc += y1[k] * l2w[k * 128 + t];
        y2[t] = fmaxf(acc, 0.f);
    }
    __syncthreads();
    if (t < 2) {
        float acc = lob[t];
        for (int k = 0; k < 128; ++k) acc += y2[k] * low[k * 2 + t];
        out[row * 2 + t] = acc;
    }
}

extern "C" void kernel_launch(void* const* d_in, const int* in_sizes, int n_in,
                              void* d_out, int out_size, void* d_ws, size_t ws_size,
                              hipStream_t stream)
{
    const float* x     = (const float*)d_in[0];
    const float* ts    = (const float*)d_in[1];
    const float* tfidf = (const float*)d_in[2];
    const float* Wall  = (const float*)d_in[3];
    const float* ball  = (const float*)d_in[4];
    const float* Uall  = (const float*)d_in[5];
    const float* bu    = (const float*)d_in[6];
    const float* Wd    = (const float*)d_in[7];
    const float* bd    = (const float*)d_in[8];
    const float* fcw   = (const float*)d_in[9];
    const float* fcb   = (const float*)d_in[10];
    const float* l1w   = (const float*)d_in[11];
    const float* l1b   = (const float*)d_in[12];
    const float* l2w   = (const float*)d_in[13];
    const float* l2b   = (const float*)d_in[14];
    const float* low   = (const float*)d_in[15];
    const float* lob   = (const float*)d_in[16];
    float* out = (float*)d_out;

    unsigned* wsu = (unsigned*)d_ws;
    unsigned* h2a = wsu;
    unsigned* h2b = h2a + BB * HH;
    unsigned* c2a = h2b + BB * HH;
    unsigned* c2b = c2a + BB * HH;
    float* hs  = (float*)(c2b + BB * HH);
    float* tsT = hs + BB * HH;
    unsigned* barv = (unsigned*)(tsT + BB * SS);                  // 1024 u32
    unsigned short* B1 = (unsigned short*)(barv + 1024);
    unsigned short* B2 = B1 + (size_t)32 * 32 * 4 * 2 * 64 * 8;   // B1 = 8.4MB
    float* uall = (float*)(B2 + (size_t)32 * 16 * 2 * 64 * 8);    // after 1MB B2
    unsigned* xpk = (unsigned*)uall;                              // union (fallback)

    const size_t need_u  = ((char*)(uall + (size_t)256 * U4PB)) - (char*)d_ws;
    const size_t need_xp = ((char*)(xpk + (size_t)BB * SS * EE)) - (char*)d_ws;
    const int use_u  = (ws_size >= need_u) ? 1 : 0;
    const int use_xp = (!use_u && ws_size >= need_xp) ? 1 : 0;

    prep_split<<<1152, 256, 0, stream>>>(Wall, Uall, Wd, B1, B2);
    if (use_u)
        u_gemm<<<512, 512, 0, stream>>>(x, xpk, 0, B1, uall);
    else if (use_xp)
        prep_pack<<<65536, 256, 0, stream>>>(x, xpk);

    void* args[] = { (void*)&x, (void*)&xpk, (void*)&use_xp, (void*)&ts,
                     (void*)&ball, (void*)&bu, (void*)&bd,
                     (void*)&B1, (void*)&B2,
                     (void*)&h2a, (void*)&h2b, (void*)&c2a, (void*)&c2b,
                     (void*)&hs, (void*)&tsT, (void*)&barv,
                     (void*)&uall, (void*)&use_u };
    hipLaunchCooperativeKernel((void*)lstm_persistent, dim3(256), dim3(512), args, 0, stream);

    tail_kernel<<<256, 256, 0, stream>>>(tfidf, hs, fcw, fcb, l1w, l1b, l2w, l2b,
                                         low, lob, out);
}